// Round 9
// baseline (64.093 us; speedup 1.0000x reference)
//
#include <hip/hip_runtime.h>

// CrossNetwork flattened (R9): out = x*scale + bsum, where
//   d_i = x.W_i ; c01 = b0.W1 ; c02 = (b0+b1).W2 ; bsum = b0+b1+b2
//   s0=d0; s1=(1+s0)d1+c01; s2=(1+s0+s1)d2+c02; scale=1+s0+s1+s2
// R9 = R8 with NITER=2: 4096 blocks x 256 threads, 4 rows/block.
// R8 (NITER=4, 2048 blocks) made the whole grid co-resident (1 generation,
// no oversubscription) and regressed to 58 us; R6 (no loop, 8192 blocks)
// was 43.5 us. This is the middle point: W/b L2 stream 393 -> 196 MB while
// keeping 2 generations of blocks for latency smoothing.

constexpr int D_DIM   = 2048;
constexpr int NT      = 256;   // threads/block; thread owns float4 cols t, t+256
constexpr int NWAVES  = 4;
constexpr int NITER   = 2;     // row-pairs per block -> 4 rows/block
constexpr int ROWS_PB = 2 * NITER;

__device__ __forceinline__ float dot8(const float4 a0, const float4 a1,
                                      const float4 b0, const float4 b1) {
    float s = a0.x * b0.x;
    s = fmaf(a0.y, b0.y, s); s = fmaf(a0.z, b0.z, s); s = fmaf(a0.w, b0.w, s);
    s = fmaf(a1.x, b1.x, s); s = fmaf(a1.y, b1.y, s);
    s = fmaf(a1.z, b1.z, s); s = fmaf(a1.w, b1.w, s);
    return s;
}

__global__ __launch_bounds__(NT, 8)
void cross_network_kernel(const float* __restrict__ x,
                          const float* __restrict__ W,
                          const float* __restrict__ bias,
                          float* __restrict__ out) {
    const int t    = threadIdx.x;
    const int lane = t & 63;
    const int wave = t >> 6;
    const int rowBase = blockIdx.x * ROWS_PB;

    // W slices live in registers for the whole block (24 VGPR).
    const float4* w0r = reinterpret_cast<const float4*>(W);
    const float4* w1r = reinterpret_cast<const float4*>(W + D_DIM);
    const float4* w2r = reinterpret_cast<const float4*>(W + 2 * D_DIM);
    const float4 w0a = w0r[t], w0b = w0r[t + NT];
    const float4 w1a = w1r[t], w1b = w1r[t + NT];
    const float4 w2a = w2r[t], w2b = w2r[t + NT];

    __shared__ float4 sbsum[2 * NT];          // b0+b1+b2 slices
    __shared__ float  sredP[2][NWAVES];       // prologue: q1,q2
    __shared__ float  sred[2][6][NWAVES];     // loop: 6 partials, dbuf

    // ---- Prologue: row-independent terms, one reduction round ----
    float q1, q2;
    {
        const float4* b0r = reinterpret_cast<const float4*>(bias);
        const float4* b1r = reinterpret_cast<const float4*>(bias + D_DIM);
        const float4* b2r = reinterpret_cast<const float4*>(bias + 2 * D_DIM);
        const float4 b0a = b0r[t], b0b = b0r[t + NT];
        const float4 b1a = b1r[t], b1b = b1r[t + NT];
        const float4 b2a = b2r[t], b2b = b2r[t + NT];
        q1 = dot8(b0a, b0b, w1a, w1b);                       // b0 . W1
        float4 sa, sb;                                       // b0+b1
        sa.x = b0a.x + b1a.x; sa.y = b0a.y + b1a.y;
        sa.z = b0a.z + b1a.z; sa.w = b0a.w + b1a.w;
        sb.x = b0b.x + b1b.x; sb.y = b0b.y + b1b.y;
        sb.z = b0b.z + b1b.z; sb.w = b0b.w + b1b.w;
        q2 = dot8(sa, sb, w2a, w2b);                         // (b0+b1) . W2
        sa.x += b2a.x; sa.y += b2a.y; sa.z += b2a.z; sa.w += b2a.w;
        sb.x += b2b.x; sb.y += b2b.y; sb.z += b2b.z; sb.w += b2b.w;
        sbsum[t]      = sa;                                  // b0+b1+b2
        sbsum[t + NT] = sb;
#pragma unroll
        for (int off = 32; off >= 1; off >>= 1) {
            q1 += __shfl_down(q1, off, 64);
            q2 += __shfl_down(q2, off, 64);
        }
        if (lane == 0) { sredP[0][wave] = q1; sredP[1][wave] = q2; }
    }
    __syncthreads();
    const float c01 = sredP[0][0] + sredP[0][1] + sredP[0][2] + sredP[0][3];
    const float c02 = sredP[1][0] + sredP[1][1] + sredP[1][2] + sredP[1][3];

    // ---- Row loop: 2 rows per iteration, one barrier per iteration ----
#pragma unroll
    for (int it = 0; it < NITER; ++it) {
        const int row0 = rowBase + 2 * it;
        const float4* xr0 = reinterpret_cast<const float4*>(x + (size_t)row0 * D_DIM);
        const float4* xr1 = reinterpret_cast<const float4*>(x + (size_t)(row0 + 1) * D_DIM);
        const float4 x0a = xr0[t], x0b = xr0[t + NT];
        const float4 x1a = xr1[t], x1b = xr1[t + NT];

        float p00 = dot8(x0a, x0b, w0a, w0b);
        float p01 = dot8(x1a, x1b, w0a, w0b);
        float p10 = dot8(x0a, x0b, w1a, w1b);
        float p11 = dot8(x1a, x1b, w1a, w1b);
        float p20 = dot8(x0a, x0b, w2a, w2b);
        float p21 = dot8(x1a, x1b, w2a, w2b);

#pragma unroll
        for (int off = 32; off >= 1; off >>= 1) {
            p00 += __shfl_down(p00, off, 64);
            p01 += __shfl_down(p01, off, 64);
            p10 += __shfl_down(p10, off, 64);
            p11 += __shfl_down(p11, off, 64);
            p20 += __shfl_down(p20, off, 64);
            p21 += __shfl_down(p21, off, 64);
        }

        float (*sr)[NWAVES] = sred[it & 1];
        if (lane == 0) {
            sr[0][wave] = p00; sr[1][wave] = p01;
            sr[2][wave] = p10; sr[3][wave] = p11;
            sr[4][wave] = p20; sr[5][wave] = p21;
        }
        __syncthreads();
        // dbuf: writes to sred[it&1] can't race reads of sred[(it-1)&1]
        // because the previous iteration's barrier separates them.

        const float d00 = sr[0][0] + sr[0][1] + sr[0][2] + sr[0][3];
        const float d01 = sr[1][0] + sr[1][1] + sr[1][2] + sr[1][3];
        const float d10 = sr[2][0] + sr[2][1] + sr[2][2] + sr[2][3];
        const float d11 = sr[3][0] + sr[3][1] + sr[3][2] + sr[3][3];
        const float d20 = sr[4][0] + sr[4][1] + sr[4][2] + sr[4][3];
        const float d21 = sr[5][0] + sr[5][1] + sr[5][2] + sr[5][3];

        float scale0, scale1;
        {
            const float t1 = 1.0f + d00;
            const float s1 = fmaf(t1, d10, c01);
            const float t2 = t1 + s1;
            const float s2 = fmaf(t2, d20, c02);
            scale0 = t2 + s2;
        }
        {
            const float t1 = 1.0f + d01;
            const float s1 = fmaf(t1, d11, c01);
            const float t2 = t1 + s1;
            const float s2 = fmaf(t2, d21, c02);
            scale1 = t2 + s2;
        }

        const float4 bsa = sbsum[t];
        const float4 bsb = sbsum[t + NT];

        float4* o0 = reinterpret_cast<float4*>(out + (size_t)row0 * D_DIM);
        float4* o1 = reinterpret_cast<float4*>(out + (size_t)(row0 + 1) * D_DIM);
        float4 v;
        v.x = fmaf(x0a.x, scale0, bsa.x); v.y = fmaf(x0a.y, scale0, bsa.y);
        v.z = fmaf(x0a.z, scale0, bsa.z); v.w = fmaf(x0a.w, scale0, bsa.w);
        o0[t] = v;
        v.x = fmaf(x0b.x, scale0, bsb.x); v.y = fmaf(x0b.y, scale0, bsb.y);
        v.z = fmaf(x0b.z, scale0, bsb.z); v.w = fmaf(x0b.w, scale0, bsb.w);
        o0[t + NT] = v;
        v.x = fmaf(x1a.x, scale1, bsa.x); v.y = fmaf(x1a.y, scale1, bsa.y);
        v.z = fmaf(x1a.z, scale1, bsa.z); v.w = fmaf(x1a.w, scale1, bsa.w);
        o1[t] = v;
        v.x = fmaf(x1b.x, scale1, bsb.x); v.y = fmaf(x1b.y, scale1, bsb.y);
        v.z = fmaf(x1b.z, scale1, bsb.z); v.w = fmaf(x1b.w, scale1, bsb.w);
        o1[t + NT] = v;
    }
}

extern "C" void kernel_launch(void* const* d_in, const int* in_sizes, int n_in,
                              void* d_out, int out_size, void* d_ws, size_t ws_size,
                              hipStream_t stream) {
    const float* x    = (const float*)d_in[0];
    const float* W    = (const float*)d_in[1];
    const float* bias = (const float*)d_in[2];
    float* out = (float*)d_out;

    const int B = in_sizes[0] / D_DIM;        // 16384
    const int blocks = B / ROWS_PB;           // 4096
    cross_network_kernel<<<blocks, NT, 0, stream>>>(x, W, bias, out);
}

// Round 10
// 43.610 us; speedup vs baseline: 1.4697x; 1.4697x over previous
//
#include <hip/hip_runtime.h>

// CrossNetwork flattened (R10 = R6 restored, the measured optimum):
//   out = x*scale + (b0+b1+b2), where
//   d_i = x.W_i ; c01 = b0.W1 ; c02 = (b0+b1).W2   (c01,c02 row-independent)
//   s0=d0; s1=(1+s0)d1+c01; s2=(1+s0+s1)d2+c02; scale=1+s0+s1+s2
// ROWS=2 rows per 256-thread block, 8192 blocks. Mapped trade-off curve
// (R1/R6/R7/R8/R9): 2 rows/block is the optimum of W-L2-traffic vs
// block-serialization/occupancy. 268 MB / 43.5 us = 6.16 TB/s = 98% of the
// measured float4-copy ceiling (6.29 TB/s) -> memory roofline.

constexpr int D_DIM    = 2048;
constexpr int NTHREADS = 256;
constexpr int ROWS     = 2;

__device__ __forceinline__ float dot8(const float4 a0, const float4 a1,
                                      const float4 b0, const float4 b1) {
    return a0.x*b0.x + a0.y*b0.y + a0.z*b0.z + a0.w*b0.w
         + a1.x*b1.x + a1.y*b1.y + a1.z*b1.z + a1.w*b1.w;
}

__global__ __launch_bounds__(NTHREADS)
void cross_network_kernel(const float* __restrict__ x,
                          const float* __restrict__ W,
                          const float* __restrict__ bias,
                          float* __restrict__ out) {
    const int row0 = blockIdx.x * ROWS;
    const int t    = threadIdx.x;
    const int lane = t & 63;
    const int wave = t >> 6;

    // Thread t owns float4 columns t and t+256 of each row.
    const float4* xr0 = reinterpret_cast<const float4*>(x + (size_t)row0 * D_DIM);
    const float4* xr1 = reinterpret_cast<const float4*>(x + (size_t)(row0 + 1) * D_DIM);
    const float4 x0a = xr0[t], x0b = xr0[t + NTHREADS];
    const float4 x1a = xr1[t], x1b = xr1[t + NTHREADS];

    const float4* w0r = reinterpret_cast<const float4*>(W);
    const float4* w1r = reinterpret_cast<const float4*>(W + D_DIM);
    const float4* w2r = reinterpret_cast<const float4*>(W + 2 * D_DIM);
    const float4* b0r = reinterpret_cast<const float4*>(bias);
    const float4* b1r = reinterpret_cast<const float4*>(bias + D_DIM);
    const float4* b2r = reinterpret_cast<const float4*>(bias + 2 * D_DIM);

    float p00, p01, p10, p11, p20, p21, q1, q2;
    float4 bsa, bsb;   // running b0 -> b0+b1 (live), small footprint
    {
        const float4 wa = w0r[t], wb = w0r[t + NTHREADS];
        p00 = dot8(x0a, x0b, wa, wb);
        p01 = dot8(x1a, x1b, wa, wb);
    }
    {
        const float4 wa = w1r[t], wb = w1r[t + NTHREADS];
        p10 = dot8(x0a, x0b, wa, wb);
        p11 = dot8(x1a, x1b, wa, wb);
        bsa = b0r[t]; bsb = b0r[t + NTHREADS];
        q1  = dot8(bsa, bsb, wa, wb);          // b0 . W1
    }
    {
        const float4 wa = w2r[t], wb = w2r[t + NTHREADS];
        p20 = dot8(x0a, x0b, wa, wb);
        p21 = dot8(x1a, x1b, wa, wb);
        const float4 b1a = b1r[t], b1b = b1r[t + NTHREADS];
        bsa.x += b1a.x; bsa.y += b1a.y; bsa.z += b1a.z; bsa.w += b1a.w;
        bsb.x += b1b.x; bsb.y += b1b.y; bsb.z += b1b.z; bsb.w += b1b.w;
        q2  = dot8(bsa, bsb, wa, wb);          // (b0+b1) . W2
    }

    // One reduction round for all 8 partials: wave butterfly + 4-wave LDS.
#pragma unroll
    for (int off = 32; off >= 1; off >>= 1) {
        p00 += __shfl_down(p00, off, 64);
        p01 += __shfl_down(p01, off, 64);
        p10 += __shfl_down(p10, off, 64);
        p11 += __shfl_down(p11, off, 64);
        p20 += __shfl_down(p20, off, 64);
        p21 += __shfl_down(p21, off, 64);
        q1  += __shfl_down(q1,  off, 64);
        q2  += __shfl_down(q2,  off, 64);
    }

    __shared__ float sred[8][4];
    if (lane == 0) {
        sred[0][wave] = p00; sred[1][wave] = p01;
        sred[2][wave] = p10; sred[3][wave] = p11;
        sred[4][wave] = p20; sred[5][wave] = p21;
        sred[6][wave] = q1;  sred[7][wave] = q2;
    }
    __syncthreads();

    float d[8];
#pragma unroll
    for (int k = 0; k < 8; ++k)
        d[k] = sred[k][0] + sred[k][1] + sred[k][2] + sred[k][3];
    const float c01 = d[6], c02 = d[7];

    float scale[ROWS];
#pragma unroll
    for (int r = 0; r < ROWS; ++r) {
        const float s0 = d[0 + r];
        const float t1 = 1.0f + s0;
        const float s1 = fmaf(t1, d[2 + r], c01);
        const float t2 = t1 + s1;
        const float s2 = fmaf(t2, d[4 + r], c02);
        scale[r] = t2 + s2;
    }

    // bsum = (b0+b1) + b2 ; out_r = x_r * scale_r + bsum
    {
        const float4 b2a = b2r[t], b2b = b2r[t + NTHREADS];
        bsa.x += b2a.x; bsa.y += b2a.y; bsa.z += b2a.z; bsa.w += b2a.w;
        bsb.x += b2b.x; bsb.y += b2b.y; bsb.z += b2b.z; bsb.w += b2b.w;
    }

    float4* o0 = reinterpret_cast<float4*>(out + (size_t)row0 * D_DIM);
    float4* o1 = reinterpret_cast<float4*>(out + (size_t)(row0 + 1) * D_DIM);
    float4 v;
    v.x = fmaf(x0a.x, scale[0], bsa.x); v.y = fmaf(x0a.y, scale[0], bsa.y);
    v.z = fmaf(x0a.z, scale[0], bsa.z); v.w = fmaf(x0a.w, scale[0], bsa.w);
    o0[t] = v;
    v.x = fmaf(x0b.x, scale[0], bsb.x); v.y = fmaf(x0b.y, scale[0], bsb.y);
    v.z = fmaf(x0b.z, scale[0], bsb.z); v.w = fmaf(x0b.w, scale[0], bsb.w);
    o0[t + NTHREADS] = v;
    v.x = fmaf(x1a.x, scale[1], bsa.x); v.y = fmaf(x1a.y, scale[1], bsa.y);
    v.z = fmaf(x1a.z, scale[1], bsa.z); v.w = fmaf(x1a.w, scale[1], bsa.w);
    o1[t] = v;
    v.x = fmaf(x1b.x, scale[1], bsb.x); v.y = fmaf(x1b.y, scale[1], bsb.y);
    v.z = fmaf(x1b.z, scale[1], bsb.z); v.w = fmaf(x1b.w, scale[1], bsb.w);
    o1[t + NTHREADS] = v;
}

extern "C" void kernel_launch(void* const* d_in, const int* in_sizes, int n_in,
                              void* d_out, int out_size, void* d_ws, size_t ws_size,
                              hipStream_t stream) {
    const float* x    = (const float*)d_in[0];
    const float* W    = (const float*)d_in[1];
    const float* bias = (const float*)d_in[2];
    float* out = (float*)d_out;

    const int B = in_sizes[0] / D_DIM;      // 16384
    cross_network_kernel<<<B / ROWS, NTHREADS, 0, stream>>>(x, W, bias, out);
}